// Round 1
// baseline (1138.486 us; speedup 1.0000x reference)
//
#include <hip/hip_runtime.h>

#define D 64
#define BN_EPS 1e-5f

// ---------------------------------------------------------------------------
// CSR build
// ---------------------------------------------------------------------------
__global__ void hist_kernel(const int* __restrict__ dst, int E, int* __restrict__ counts) {
    int i = blockIdx.x * blockDim.x + threadIdx.x;
    if (i < E) atomicAdd(&counts[dst[i]], 1);
}

__global__ void dinv_kernel(const int* __restrict__ counts, float* __restrict__ dinv, int N) {
    int i = blockIdx.x * blockDim.x + threadIdx.x;
    if (i < N) dinv[i] = rsqrtf((float)(counts[i] + 1)); // +1 self loop
}

// inclusive block scan of counts; rowptr[i+1] = incl(i) (pre-offset); bsums[b] = block total
__global__ void scan1_kernel(const int* __restrict__ counts, int N,
                             int* __restrict__ rowptr, int* __restrict__ bsums) {
    __shared__ int s[256];
    int i = blockIdx.x * 256 + threadIdx.x;
    int v = (i < N) ? counts[i] : 0;
    s[threadIdx.x] = v;
    __syncthreads();
    for (int off = 1; off < 256; off <<= 1) {
        int t = (threadIdx.x >= off) ? s[threadIdx.x - off] : 0;
        __syncthreads();
        s[threadIdx.x] += t;
        __syncthreads();
    }
    if (i < N) rowptr[i + 1] = s[threadIdx.x];
    if (threadIdx.x == 255) bsums[blockIdx.x] = s[255];
}

// single-block exclusive scan of block sums (nb <= 512)
__global__ void scan2_kernel(const int* __restrict__ bsums, int nb, int* __restrict__ boff) {
    __shared__ int s[512];
    int v = (threadIdx.x < nb) ? bsums[threadIdx.x] : 0;
    s[threadIdx.x] = v;
    __syncthreads();
    for (int off = 1; off < 512; off <<= 1) {
        int t = (threadIdx.x >= off) ? s[threadIdx.x - off] : 0;
        __syncthreads();
        s[threadIdx.x] += t;
        __syncthreads();
    }
    if (threadIdx.x < nb) boff[threadIdx.x] = s[threadIdx.x] - v; // exclusive
}

__global__ void scan3_kernel(int* __restrict__ rowptr, const int* __restrict__ boff, int N) {
    int i = blockIdx.x * 256 + threadIdx.x;
    if (i == 0) rowptr[0] = 0;
    if (i < N) rowptr[i + 1] += boff[i >> 8];
}

__global__ void copy_kernel(const int* __restrict__ src, int* __restrict__ dst, int n) {
    int i = blockIdx.x * blockDim.x + threadIdx.x;
    if (i < n) dst[i] = src[i];
}

__global__ void fill_kernel(const int* __restrict__ esrc, const int* __restrict__ edst, int E,
                            int* __restrict__ cursor, int* __restrict__ col) {
    int e = blockIdx.x * blockDim.x + threadIdx.x;
    if (e < E) {
        int d = edst[e];
        int p = atomicAdd(&cursor[d], 1);
        col[p] = esrc[e];
    }
}

// ---------------------------------------------------------------------------
// Per-layer kernels
// ---------------------------------------------------------------------------
// out[r][j] = sum_k act(in[r][k]) * W[k][j];  act = BN-affine + relu (if BN)
template <bool BN>
__global__ __launch_bounds__(256) void gemm_kernel(const float* __restrict__ in,
                                                   const float* __restrict__ W,
                                                   const float* __restrict__ bnp, // scale[64],shift[64]
                                                   float* __restrict__ out, int N) {
    __shared__ float Wl[D][D];
    for (int i = threadIdx.x; i < D * D / 4; i += 256) {
        ((float4*)&Wl[0][0])[i] = ((const float4*)W)[i];
    }
    int lane = threadIdx.x & 63;
    float scale = 1.f, shift = 0.f;
    if (BN) { scale = bnp[lane]; shift = bnp[64 + lane]; }
    __syncthreads();

    int wid = (blockIdx.x * blockDim.x + threadIdx.x) >> 6;
    int nw  = (gridDim.x * blockDim.x) >> 6;
    for (int r = wid; r < N; r += nw) {
        float v = in[r * D + lane];
        if (BN) v = fmaxf(fmaf(v, scale, shift), 0.f);
        float acc = 0.f;
#pragma unroll
        for (int k = 0; k < D; ++k) {
            float bk = __shfl(v, k);
            acc = fmaf(bk, Wl[k][lane], acc);
        }
        out[r * D + lane] = acc;
    }
}

// one wave per node; lane j owns feature j
__global__ __launch_bounds__(256) void agg_kernel(const float* __restrict__ hW,
                                                  const int* __restrict__ rowptr,
                                                  const int* __restrict__ col,
                                                  const float* __restrict__ dinv,
                                                  float* __restrict__ out, int N) {
    int lane = threadIdx.x & 63;
    int n = (blockIdx.x * blockDim.x + threadIdx.x) >> 6;
    if (n >= N) return;
    float di = dinv[n];
    float acc = hW[n * D + lane] * di * di; // self loop
    int e0 = rowptr[n], e1 = rowptr[n + 1];
    for (int e = e0; e < e1; ++e) {
        int s = col[e];
        float w = dinv[s] * di;
        acc = fmaf(hW[s * D + lane], w, acc);
    }
    out[n * D + lane] = acc;
}

__global__ __launch_bounds__(256) void bn_stats_kernel(const float* __restrict__ h, int N,
                                                       float* __restrict__ stats) { // sum[64],sumsq[64]
    int f = threadIdx.x & 63;
    int g = threadIdx.x >> 6; // 0..3
    float s = 0.f, s2 = 0.f;
    for (int r = blockIdx.x * 4 + g; r < N; r += gridDim.x * 4) {
        float v = h[r * D + f];
        s += v;
        s2 += v * v;
    }
    __shared__ float red[4][128];
    red[g][f] = s;
    red[g][64 + f] = s2;
    __syncthreads();
    if (g == 0) {
        s  = red[0][f] + red[1][f] + red[2][f] + red[3][f];
        s2 = red[0][64 + f] + red[1][64 + f] + red[2][64 + f] + red[3][64 + f];
        atomicAdd(&stats[f], s);
        atomicAdd(&stats[64 + f], s2);
    }
}

__global__ void bn_finalize_kernel(const float* __restrict__ stats,
                                   const float* __restrict__ gamma,
                                   const float* __restrict__ beta,
                                   int N, float* __restrict__ bnp) {
    int f = threadIdx.x; // 64 threads
    float invN = 1.f / (float)N;
    float mean = stats[f] * invN;
    float var  = stats[64 + f] * invN - mean * mean;
    float sc   = gamma[f] * rsqrtf(var + BN_EPS);
    bnp[f]      = sc;
    bnp[64 + f] = beta[f] - mean * sc;
}

__global__ __launch_bounds__(256) void norm_relu_kernel(float* __restrict__ h,
                                                        const float* __restrict__ bnp, int total) {
    int i = blockIdx.x * blockDim.x + threadIdx.x;
    if (i < total) {
        int f = i & 63;
        h[i] = fmaxf(fmaf(h[i], bnp[f], bnp[64 + f]), 0.f);
    }
}

// ---------------------------------------------------------------------------
extern "C" void kernel_launch(void* const* d_in, const int* in_sizes, int n_in,
                              void* d_out, int out_size, void* d_ws, size_t ws_size,
                              hipStream_t stream) {
    const float* x      = (const float*)d_in[0];
    const int*   ei     = (const int*)d_in[1];
    const float* Ws     = (const float*)d_in[2];
    // d_in[3] = bs: cancels exactly under training-mode BatchNorm (h+b - mean(h+b) == h - mean(h))
    const float* gammas = (const float*)d_in[4];
    const float* betas  = (const float*)d_in[5];

    const int N = in_sizes[0] / D;       // 100000
    const int E = in_sizes[1] / 2;       // 1250000
    const int DEPTH = in_sizes[2] / (D * D); // 4

    const int* esrc = ei;       // edge_index[0]
    const int* edst = ei + E;   // edge_index[1]

    // ---- workspace carve-up (256B aligned) ----
    char* w = (char*)d_ws;
    size_t off = 0;
    auto alloc = [&](size_t bytes) {
        void* p = w + off;
        off = (off + bytes + 255) & ~(size_t)255;
        return p;
    };
    float* hW     = (float*)alloc((size_t)N * D * sizeof(float)); // 25.6 MB
    int*   counts = (int*)alloc((size_t)N * sizeof(int));
    int*   rowptr = (int*)alloc((size_t)(N + 1) * sizeof(int));
    int*   cursor = (int*)alloc((size_t)(N + 1) * sizeof(int));
    float* dinv   = (float*)alloc((size_t)N * sizeof(float));
    int*   col    = (int*)alloc((size_t)E * sizeof(int));
    int*   bsums  = (int*)alloc(512 * sizeof(int));
    int*   boff   = (int*)alloc(512 * sizeof(int));
    float* stats  = (float*)alloc(128 * sizeof(float));
    float* bnp    = (float*)alloc(128 * sizeof(float));
    float* A      = (float*)d_out; // ping-pong buffer A lives in d_out

    const int nbScan = (N + 255) / 256; // 391

    // ---- degree + CSR ----
    hipMemsetAsync(counts, 0, (size_t)N * sizeof(int), stream);
    hist_kernel<<<(E + 255) / 256, 256, 0, stream>>>(edst, E, counts);
    dinv_kernel<<<(N + 255) / 256, 256, 0, stream>>>(counts, dinv, N);
    scan1_kernel<<<nbScan, 256, 0, stream>>>(counts, N, rowptr, bsums);
    scan2_kernel<<<1, 512, 0, stream>>>(bsums, nbScan, boff);
    scan3_kernel<<<nbScan, 256, 0, stream>>>(rowptr, boff, N);
    copy_kernel<<<(N + 255) / 256, 256, 0, stream>>>(rowptr, cursor, N);
    fill_kernel<<<(E + 255) / 256, 256, 0, stream>>>(esrc, edst, E, cursor, col);

    // ---- layers ----
    const int gemmBlocks = 1024;
    const int aggBlocks  = (N + 3) / 4;
    const int statBlocks = 512;
    for (int l = 0; l < DEPTH; ++l) {
        const float* W = Ws + (size_t)l * D * D;
        if (l == 0)
            gemm_kernel<false><<<gemmBlocks, 256, 0, stream>>>(x, W, bnp, hW, N);
        else
            gemm_kernel<true><<<gemmBlocks, 256, 0, stream>>>(A, W, bnp, hW, N);
        agg_kernel<<<aggBlocks, 256, 0, stream>>>(hW, rowptr, col, dinv, A, N);
        hipMemsetAsync(stats, 0, 128 * sizeof(float), stream);
        bn_stats_kernel<<<statBlocks, 256, 0, stream>>>(A, N, stats);
        bn_finalize_kernel<<<1, 64, 0, stream>>>(stats, gammas + l * D, betas + l * D, N, bnp);
    }
    // final BN + relu applied in place on d_out
    norm_relu_kernel<<<(N * D + 255) / 256, 256, 0, stream>>>(A, bnp, N * D);
}